// Round 1
// baseline (2675.060 us; speedup 1.0000x reference)
//
#include <hip/hip_runtime.h>
#include <stdint.h>
#include <math.h>

// Match numpy's non-fused multiply-add rounding in distance/plane tests:
// a wrong argmin (or a boundary-mask flip) cascades into an O(1) output error.
#pragma clang fp contract(off)

#define BLOCK 1024
#define NWAVES (BLOCK / 64)
#define MAX_ITERS 50
#define EPS_NORM 1e-8f
#define EPS_SEP (-1e-6f)

// One block per target. Per-target active mask (N bits) lives in LDS.
// Each pass fuses: mask update for plane k (dot >= EPS_SEP => separated)
// with the argmin for iteration k+1 (which needs exactly the updated mask).
__global__ __launch_bounds__(BLOCK, 1) void convex_plane_kernel(
    const float* __restrict__ pc, const float* __restrict__ tg,
    float* __restrict__ out, int N, int M)
{
    extern __shared__ uint32_t smem[];
    const int tid  = threadIdx.x;
    const int lane = tid & 63;
    const int wv   = tid >> 6;
    const int m    = blockIdx.x;

    const int steps = (N + BLOCK - 1) / BLOCK;
    const int W     = (steps * BLOCK) >> 5;   // mask words (padded; tail bits stay 0)

    uint32_t* mask  = smem;                   // [W]
    float*    red_d = (float*)(smem + W);     // [NWAVES]
    int*      red_i = (int*)(red_d + NWAVES); // [NWAVES]
    int*      bcast = red_i + NWAVES;         // [1]

    const float tx = tg[3*m+0], ty = tg[3*m+1], tz = tg[3*m+2];
    const float t2 = tx*tx + ty*ty + tz*tz;

    float* out_a = out;
    float* out_b = out + (size_t)MAX_ITERS * (size_t)M * 3;

    // Fused scan: writes new mask (ballot; lanes 0/32 own the two words per
    // wave-chunk of 64 consecutive points) and returns argmin of
    // d2 = t2 + p2 - 2*t.p over surviving points. first=true: all-valid pass
    // that also initializes the mask. Empty set -> idx 0 (numpy argmin of inf).
    auto scan = [&](bool first, float ax, float ay, float az, float b) -> int {
        float dmin = INFINITY;
        int   imin = 0;
        for (int s = 0; s < steps; ++s) {
            const int i = s * BLOCK + tid;
            const bool valid = (i < N);
            bool active = false;
            if (first) active = valid;
            else if (valid) active = (mask[i >> 5] >> (i & 31)) & 1u;

            bool  keep = false;
            float px = 0.f, py = 0.f, pz = 0.f;
            if (active) {
                px = pc[3*i + 0]; py = pc[3*i + 1]; pz = pc[3*i + 2];
                if (first) keep = true;
                else {
                    float dt = ax*px + ay*py + az*pz - b;
                    keep = (dt < EPS_SEP);   // !(dt >= EPS_SEP), NaN-free
                }
            }
            unsigned long long bal = __ballot(keep);
            const int wbase = (s * BLOCK + (wv << 6)) >> 5;
            if (lane == 0)       mask[wbase]     = (uint32_t)bal;
            else if (lane == 32) mask[wbase + 1] = (uint32_t)(bal >> 32);

            if (keep) {
                float p2 = px*px + py*py + pz*pz;
                float tp = tx*px + ty*py + tz*pz;
                float d2 = t2 + p2 - 2.0f*tp;    // reference's exact form
                if (d2 < dmin) { dmin = d2; imin = i; }  // ascending i => first-index ties
            }
        }
        // wave-level lexicographic (d2, idx) reduction
        #pragma unroll
        for (int off = 32; off > 0; off >>= 1) {
            float od = __shfl_down(dmin, off, 64);
            int   oi = __shfl_down(imin, off, 64);
            if (od < dmin || (od == dmin && oi < imin)) { dmin = od; imin = oi; }
        }
        if (lane == 0) { red_d[wv] = dmin; red_i[wv] = imin; }
        __syncthreads();
        if (tid == 0) {
            float bd = red_d[0]; int bi = red_i[0];
            for (int w2 = 1; w2 < NWAVES; ++w2) {
                float od = red_d[w2]; int oi = red_i[w2];
                if (od < bd || (od == bd && oi < bi)) { bd = od; bi = oi; }
            }
            bcast[0] = bi;
        }
        __syncthreads();
        return bcast[0];
    };

    int idx = scan(true, 0.f, 0.f, 0.f, 0.f);
    for (int k = 0; k < MAX_ITERS; ++k) {
        const float cx = pc[3*idx+0], cy = pc[3*idx+1], cz = pc[3*idx+2];
        const float vx = cx - tx, vy = cy - ty, vz = cz - tz;
        const float nrm = sqrtf(vx*vx + vy*vy + vz*vz);
        const float den = nrm + EPS_NORM;
        const float ax = vx / den, ay = vy / den, az = vz / den;
        const float b  = ax*cx + ay*cy + az*cz;   // reference: b = sum(a * closest)
        if (tid == 0) {
            const size_t oa = ((size_t)k * M + m) * 3;
            out_a[oa+0] = ax; out_a[oa+1] = ay; out_a[oa+2] = az;
            out_b[(size_t)k * M + m] = b;
        }
        if (k + 1 < MAX_ITERS)                    // last update is unobservable
            idx = scan(false, ax, ay, az, b);
    }
}

extern "C" void kernel_launch(void* const* d_in, const int* in_sizes, int n_in,
                              void* d_out, int out_size, void* d_ws, size_t ws_size,
                              hipStream_t stream) {
    const float* pc = (const float*)d_in[0];
    const float* tg = (const float*)d_in[1];
    float* out = (float*)d_out;
    const int N = in_sizes[0] / 3;
    const int M = in_sizes[1] / 3;
    const int steps = (N + BLOCK - 1) / BLOCK;
    const size_t smem = (size_t)((steps * BLOCK) >> 5) * sizeof(uint32_t)
                      + NWAVES * (sizeof(float) + sizeof(int)) + sizeof(int);
    convex_plane_kernel<<<M, BLOCK, smem, stream>>>(pc, tg, out, N, M);
}

// Round 2
// 862.927 us; speedup vs baseline: 3.1000x; 3.1000x over previous
//
#include <hip/hip_runtime.h>
#include <stdint.h>
#include <math.h>

// Match numpy's non-fused multiply-add rounding in distance/plane tests:
// a wrong argmin (or a boundary-mask flip) cascades into an O(1) output error.
// R1 passed with absmax 0.0 using exactly these expression forms — keep them.
#pragma clang fp contract(off)

#define BLOCK 1024
#define NWAVES (BLOCK / 64)
#define MAX_ITERS 50
#define EPS_NORM 1e-8f
#define EPS_SEP (-1e-6f)

// One block per target.
// Phase A: full-N scans with an LDS bitmask (as R1), plus survivor-count and
//          best-effort compacted index-list building (ballot prefix + 1 LDS
//          atomic per wave per step).
// Phase B: once survivors <= CAP, scan only the compacted list, re-compacting
//          in place (survivor counts halve per cut -> work ~ O(N) total
//          instead of O(50*N)).
__global__ __launch_bounds__(BLOCK, 1) void convex_plane_kernel(
    const float* __restrict__ pc, const float* __restrict__ tg,
    float* __restrict__ out, int N, int M, int CAP)
{
    extern __shared__ uint32_t smem[];
    const int tid  = threadIdx.x;
    const int lane = tid & 63;
    const int wv   = tid >> 6;
    const int m    = blockIdx.x;

    const int steps = (N + BLOCK - 1) / BLOCK;
    const int W     = (steps * BLOCK) >> 5;   // mask words (padded; tail bits 0)

    uint32_t* mask  = smem;                    // [W]
    int*      list  = (int*)(smem + W);        // [CAP]
    float*    red_d = (float*)(list + CAP);    // [NWAVES]
    int*      red_i = (int*)(red_d + NWAVES);  // [NWAVES]
    int*      bcast = red_i + NWAVES;          // [1]
    int*      cnt   = bcast + 1;               // [1] survivor counter

    const float tx = tg[3*m+0], ty = tg[3*m+1], tz = tg[3*m+2];
    const float t2 = tx*tx + ty*ty + tz*tz;

    float* out_a = out;
    float* out_b = out + (size_t)MAX_ITERS * (size_t)M * 3;

    // block-wide lexicographic (d2, idx) argmin + broadcast.
    auto reduce_idx = [&](float dmin, int imin) -> int {
        #pragma unroll
        for (int off = 32; off > 0; off >>= 1) {
            float od = __shfl_down(dmin, off, 64);
            int   oi = __shfl_down(imin, off, 64);
            if (od < dmin || (od == dmin && oi < imin)) { dmin = od; imin = oi; }
        }
        if (lane == 0) { red_d[wv] = dmin; red_i[wv] = imin; }
        __syncthreads();
        if (tid == 0) {
            float bd = red_d[0]; int bi = red_i[0];
            for (int w2 = 1; w2 < NWAVES; ++w2) {
                float od = red_d[w2]; int oi = red_i[w2];
                if (od < bd || (od == bd && oi < bi)) { bd = od; bi = oi; }
            }
            bcast[0] = bi;
        }
        __syncthreads();
        return bcast[0];
    };

    // Phase A scan: full-N pass over the bitmask; updates mask, appends
    // survivors to list (valid only if final cnt <= CAP), returns argmin.
    auto scanA = [&](bool first, float ax, float ay, float az, float b) -> int {
        if (tid == 0) cnt[0] = 0;
        __syncthreads();
        float dmin = INFINITY;
        int   imin = 0;
        for (int s = 0; s < steps; ++s) {
            const int i = s * BLOCK + tid;
            bool active;
            if (first) active = (i < N);
            else       active = (mask[i >> 5] >> (i & 31)) & 1u;

            bool  keep = false;
            float px = 0.f, py = 0.f, pz = 0.f;
            if (active) {
                px = pc[3*i + 0]; py = pc[3*i + 1]; pz = pc[3*i + 2];
                if (first) keep = true;
                else {
                    float dt = ax*px + ay*py + az*pz - b;
                    keep = (dt < EPS_SEP);          // !(dt >= EPS_SEP)
                }
            }
            unsigned long long bal = __ballot(keep);
            const int wbase = (s * BLOCK + (wv << 6)) >> 5;
            if (lane == 0)       mask[wbase]     = (uint32_t)bal;
            else if (lane == 32) mask[wbase + 1] = (uint32_t)(bal >> 32);

            int base = 0;
            if (lane == 0) base = atomicAdd(cnt, (int)__popcll(bal));
            base = __shfl(base, 0, 64);

            if (keep) {
                int pos = base + (int)__popcll(bal & ((1ull << lane) - 1ull));
                if (pos < CAP) list[pos] = i;
                float p2 = px*px + py*py + pz*pz;
                float tp = tx*px + ty*py + tz*pz;
                float d2 = t2 + p2 - 2.0f*tp;       // reference's exact form
                if (d2 < dmin) { dmin = d2; imin = i; }
            }
        }
        return reduce_idx(dmin, imin);
    };

    // Phase B scan: iterate only the compacted survivor list; re-compact in
    // place. In-place is safe: per step, all reads of segment s complete
    // (barrier) before atomic-append writes, and write positions are provably
    // < start of any unread segment (cumulative survivors <= cumulative reads).
    auto scanB = [&](int count, float ax, float ay, float az, float b) -> int {
        if (tid == 0) cnt[0] = 0;
        __syncthreads();
        float dmin = INFINITY;
        int   imin = 0;
        const int bsteps = (count + BLOCK - 1) / BLOCK;
        for (int s = 0; s < bsteps; ++s) {
            const int e = s * BLOCK + tid;
            bool keep = false; int j = 0; float d2 = 0.f;
            if (e < count) {
                j = list[e];
                float px = pc[3*j + 0], py = pc[3*j + 1], pz = pc[3*j + 2];
                float dt = ax*px + ay*py + az*pz - b;
                if (dt < EPS_SEP) {
                    keep = true;
                    float p2 = px*px + py*py + pz*pz;
                    float tp = tx*px + ty*py + tz*pz;
                    d2 = t2 + p2 - 2.0f*tp;
                }
            }
            __syncthreads();                        // reads done before writes
            unsigned long long bal = __ballot(keep);
            int base = 0;
            if (lane == 0) base = atomicAdd(cnt, (int)__popcll(bal));
            base = __shfl(base, 0, 64);
            if (keep) {
                int pos = base + (int)__popcll(bal & ((1ull << lane) - 1ull));
                list[pos] = j;
                if (d2 < dmin) { dmin = d2; imin = j; }
            }
        }
        return reduce_idx(dmin, imin);
    };

    bool comp = false;
    int  count = 0;
    int  idx = scanA(true, 0.f, 0.f, 0.f, 0.f);
    count = cnt[0];
    if (count <= CAP) comp = true;                  // (never at k=0 for N>CAP)

    for (int k = 0; k < MAX_ITERS; ++k) {
        const float cx = pc[3*idx+0], cy = pc[3*idx+1], cz = pc[3*idx+2];
        const float vx = cx - tx, vy = cy - ty, vz = cz - tz;
        const float nrm = sqrtf(vx*vx + vy*vy + vz*vz);
        const float den = nrm + EPS_NORM;
        const float ax = vx / den, ay = vy / den, az = vz / den;
        const float b  = ax*cx + ay*cy + az*cz;     // b = sum(a * closest)
        if (tid == 0) {
            const size_t oa = ((size_t)k * M + m) * 3;
            out_a[oa+0] = ax; out_a[oa+1] = ay; out_a[oa+2] = az;
            out_b[(size_t)k * M + m] = b;
        }
        if (k + 1 < MAX_ITERS) {                    // last update unobservable
            idx = comp ? scanB(count, ax, ay, az, b)
                       : scanA(false, ax, ay, az, b);
            count = cnt[0];
            if (count <= CAP) comp = true;
        }
    }
}

extern "C" void kernel_launch(void* const* d_in, const int* in_sizes, int n_in,
                              void* d_out, int out_size, void* d_ws, size_t ws_size,
                              hipStream_t stream) {
    const float* pc = (const float*)d_in[0];
    const float* tg = (const float*)d_in[1];
    float* out = (float*)d_out;
    const int N = in_sizes[0] / 3;
    const int M = in_sizes[1] / 3;
    const int steps = (N + BLOCK - 1) / BLOCK;
    const size_t maskB = (size_t)((steps * BLOCK) >> 5) * sizeof(uint32_t);
    const size_t fixedB = NWAVES * (sizeof(float) + sizeof(int)) + 2 * sizeof(int);

    int CAP = 32768;                                // 128 KB list -> ~153 KB LDS
    size_t smem = maskB + (size_t)CAP * sizeof(int) + fixedB;
    if (hipFuncSetAttribute((const void*)convex_plane_kernel,
                            hipFuncAttributeMaxDynamicSharedMemorySize,
                            (int)smem) != hipSuccess) {
        CAP = 8192;                                 // stay within default 64 KB
        smem = maskB + (size_t)CAP * sizeof(int) + fixedB;
    }
    convex_plane_kernel<<<M, BLOCK, smem, stream>>>(pc, tg, out, N, M, CAP);
}

// Round 3
// 655.247 us; speedup vs baseline: 4.0825x; 1.3170x over previous
//
#include <hip/hip_runtime.h>
#include <stdint.h>
#include <math.h>

// Match numpy's non-fused multiply-add rounding in distance/plane tests:
// a wrong argmin (or a boundary-mask flip) cascades into an O(1) output error.
// R1/R2 passed with absmax 0.0 using exactly these expression forms — keep them.
#pragma clang fp contract(off)

#define BLOCK 1024
#define NW (BLOCK / 64)
#define MAX_ITERS 50
#define EPS_NORM 1e-8f
#define EPS_SEP (-1e-6f)

// One block per target.
// Phase A: lean full-N bitmask scans (no atomics); survivor count via register
//          popcounts folded into the argmin reduce. When incoming count fits
//          2*CAP, the scan opportunistically also compacts survivors into an
//          LDS index list (ballot prefix + 1 atomic/wave/step) — at most ~2
//          scans ever pay this.
// Phase B: scan only the compacted list, re-compacting in place; counts halve
//          per cut so total list work is O(CAP).
// Early-out: empty set => all remaining (a,b) identical; bulk-write and exit.
// NOTE: idx+count are returned through the barrier-protected bcast[] — do NOT
// read cnt[] from caller code (races with the next scan's reset).
__global__ __launch_bounds__(BLOCK, 1) void convex_plane_kernel(
    const float* __restrict__ pc, const float* __restrict__ tg,
    float* __restrict__ out, int N, int M, int CAP)
{
    extern __shared__ uint32_t smem[];
    const int tid  = threadIdx.x;
    const int lane = tid & 63;
    const int wv   = tid >> 6;
    const int m    = blockIdx.x;

    const int steps = (N + BLOCK - 1) / BLOCK;
    const int W     = (steps * BLOCK) >> 5;    // mask words (padded; tail bits 0)

    uint32_t* mask  = smem;                    // [W]
    int*      list  = (int*)(smem + W);        // [CAP]
    float*    red_d = (float*)(list + CAP);    // [NW]
    int*      red_i = (int*)(red_d + NW);      // [NW]
    int*      cw    = red_i + NW;              // [NW] per-wave survivor counts
    int*      bcast = cw + NW;                 // [2] {argmin idx, total count}
    int*      cnt   = bcast + 2;               // [1] list-append cursor

    const float tx = tg[3*m+0], ty = tg[3*m+1], tz = tg[3*m+2];
    const float t2 = tx*tx + ty*ty + tz*tz;

    float* out_a = out;
    float* out_b = out + (size_t)MAX_ITERS * (size_t)M * 3;

    // per-wave lexicographic (d2, idx) argmin, result in lane 0
    auto wave_red = [&](float& dmin, int& imin) {
        #pragma unroll
        for (int off = 32; off > 0; off >>= 1) {
            float od = __shfl_down(dmin, off, 64);
            int   oi = __shfl_down(imin, off, 64);
            if (od < dmin || (od == dmin && oi < imin)) { dmin = od; imin = oi; }
        }
    };

    // cross-wave finish: argmin + count-sum; returns {idx, count} to ALL
    // threads via bcast, read inside the barrier window (race-safe).
    auto finish = [&](float dmin, int imin, int mycnt) -> int2 {
        wave_red(dmin, imin);
        if (lane == 0) { red_d[wv] = dmin; red_i[wv] = imin; cw[wv] = mycnt; }
        __syncthreads();
        if (wv == 0) {
            float bd = (lane < NW) ? red_d[lane] : INFINITY;
            int   bi = (lane < NW) ? red_i[lane] : 0;
            int   c  = (lane < NW) ? cw[lane]    : 0;
            #pragma unroll
            for (int off = 8; off > 0; off >>= 1) {
                float od = __shfl_down(bd, off, 64);
                int   oi = __shfl_down(bi, off, 64);
                int   oc = __shfl_down(c,  off, 64);
                if (od < bd || (od == bd && oi < bi)) { bd = od; bi = oi; }
                c += oc;
            }
            if (lane == 0) { bcast[0] = bi; bcast[1] = c; }
        }
        __syncthreads();
        int2 r; r.x = bcast[0]; r.y = bcast[1];
        return r;
    };

    // Phase A: full-N scan over the bitmask. Updates mask; optionally builds
    // the compacted list (valid iff returned count <= CAP).
    auto scanA = [&](bool first, bool build,
                     float ax, float ay, float az, float b) -> int2 {
        if (build && tid == 0) cnt[0] = 0;
        __syncthreads();
        float dmin = INFINITY;
        int   imin = 0;
        int   mycnt = 0;
        for (int s = 0; s < steps; ++s) {
            const int i = s * BLOCK + tid;
            bool active = first ? (i < N)
                                : (((mask[i >> 5] >> (i & 31)) & 1u) != 0u);
            bool  keep = false;
            float px = 0.f, py = 0.f, pz = 0.f;
            if (active) {
                const float* p = pc + 3 * (size_t)i;
                px = p[0]; py = p[1]; pz = p[2];
                if (first) keep = true;
                else {
                    float dt = ax*px + ay*py + az*pz - b;
                    keep = (dt < EPS_SEP);           // !(dt >= EPS_SEP)
                }
            }
            unsigned long long bal = __ballot(keep);
            const int wbase = (s * BLOCK + (wv << 6)) >> 5;
            if (lane == 0)       mask[wbase]     = (uint32_t)bal;
            else if (lane == 32) mask[wbase + 1] = (uint32_t)(bal >> 32);
            mycnt += (int)__popcll(bal);             // same value on all lanes

            if (build) {
                int base = 0;
                if (lane == 0) base = atomicAdd(cnt, (int)__popcll(bal));
                base = __shfl(base, 0, 64);
                if (keep) {
                    int pos = base + (int)__popcll(bal & ((1ull << lane) - 1ull));
                    if (pos < CAP) list[pos] = i;
                }
            }
            if (keep) {
                float p2 = px*px + py*py + pz*pz;
                float tp = tx*px + ty*py + tz*pz;
                float d2 = t2 + p2 - 2.0f*tp;        // reference's exact form
                if (d2 < dmin) { dmin = d2; imin = i; }  // ascending i => first-idx
            }
        }
        return finish(dmin, imin, mycnt);
    };

    // Phase B: scan only the compacted list; re-compact in place. Safe:
    // per step, reads of segment s complete (barrier) before appends, and
    // append positions never exceed the start of any unread segment.
    auto scanB = [&](int count, float ax, float ay, float az, float b) -> int2 {
        if (tid == 0) cnt[0] = 0;
        __syncthreads();
        float dmin = INFINITY;
        int   imin = 0;
        const int bsteps = (count + BLOCK - 1) / BLOCK;
        for (int s = 0; s < bsteps; ++s) {
            const int e = s * BLOCK + tid;
            bool keep = false; int j = 0; float d2v = 0.f;
            if (e < count) {
                j = list[e];
                const float* p = pc + 3 * (size_t)j;
                float px = p[0], py = p[1], pz = p[2];
                float dt = ax*px + ay*py + az*pz - b;
                if (dt < EPS_SEP) {
                    keep = true;
                    float p2 = px*px + py*py + pz*pz;
                    float tp = tx*px + ty*py + tz*pz;
                    d2v = t2 + p2 - 2.0f*tp;
                }
            }
            __syncthreads();                         // reads done before writes
            unsigned long long bal = __ballot(keep);
            int base = 0;
            if (lane == 0) base = atomicAdd(cnt, (int)__popcll(bal));
            base = __shfl(base, 0, 64);
            if (keep) {
                int pos = base + (int)__popcll(bal & ((1ull << lane) - 1ull));
                list[pos] = j;
                // list order is arbitrary -> lexicographic update for exact ties
                if (d2v < dmin || (d2v == dmin && j < imin)) { dmin = d2v; imin = j; }
            }
        }
        __syncthreads();                             // all appends/atomics done
        wave_red(dmin, imin);
        if (lane == 0) { red_d[wv] = dmin; red_i[wv] = imin; }
        __syncthreads();
        if (wv == 0) {
            float bd = (lane < NW) ? red_d[lane] : INFINITY;
            int   bi = (lane < NW) ? red_i[lane] : 0;
            #pragma unroll
            for (int off = 8; off > 0; off >>= 1) {
                float od = __shfl_down(bd, off, 64);
                int   oi = __shfl_down(bi, off, 64);
                if (od < bd || (od == bd && oi < bi)) { bd = od; bi = oi; }
            }
            if (lane == 0) { bcast[0] = bi; bcast[1] = cnt[0]; }
        }
        __syncthreads();
        int2 r; r.x = bcast[0]; r.y = bcast[1];
        return r;
    };

    bool comp = false;
    int2 rc = scanA(true, false, 0.f, 0.f, 0.f, 0.f);
    int idx = rc.x, count = rc.y;                    // count = N here

    for (int k = 0; k < MAX_ITERS; ++k) {
        const float cx = pc[3*idx+0], cy = pc[3*idx+1], cz = pc[3*idx+2];
        const float vx = cx - tx, vy = cy - ty, vz = cz - tz;
        const float nrm = sqrtf(vx*vx + vy*vy + vz*vz);
        const float den = nrm + EPS_NORM;
        const float ax = vx / den, ay = vy / den, az = vz / den;
        const float b  = ax*cx + ay*cy + az*cz;      // b = sum(a * closest)

        if (count == 0) {
            // Set was empty when idx was computed (idx==0): every remaining
            // iteration emits these exact values. Bulk-write and retire.
            for (int q = tid; q < MAX_ITERS - k; q += BLOCK) {
                const int kk = k + q;
                const size_t oa = ((size_t)kk * M + m) * 3;
                out_a[oa+0] = ax; out_a[oa+1] = ay; out_a[oa+2] = az;
                out_b[(size_t)kk * M + m] = b;
            }
            return;
        }
        if (tid == 0) {
            const size_t oa = ((size_t)k * M + m) * 3;
            out_a[oa+0] = ax; out_a[oa+1] = ay; out_a[oa+2] = az;
            out_b[(size_t)k * M + m] = b;
        }
        if (k + 1 < MAX_ITERS) {                     // last update unobservable
            if (comp) {
                rc = scanB(count, ax, ay, az, b);
            } else {
                const bool build = (count <= 2 * CAP);   // opportunistic compact
                rc = scanA(false, build, ax, ay, az, b);
                if (build && rc.y <= CAP) comp = true;
            }
            idx = rc.x; count = rc.y;
        }
    }
}

extern "C" void kernel_launch(void* const* d_in, const int* in_sizes, int n_in,
                              void* d_out, int out_size, void* d_ws, size_t ws_size,
                              hipStream_t stream) {
    const float* pc = (const float*)d_in[0];
    const float* tg = (const float*)d_in[1];
    float* out = (float*)d_out;
    const int N = in_sizes[0] / 3;
    const int M = in_sizes[1] / 3;
    const int steps = (N + BLOCK - 1) / BLOCK;
    const size_t maskB  = (size_t)((steps * BLOCK) >> 5) * sizeof(uint32_t);
    const size_t fixedB = NW * (2 * sizeof(int) + sizeof(float)) + 3 * sizeof(int);

    int CAP = 32768;                                 // 128 KB list -> ~153 KB LDS
    size_t smem = maskB + (size_t)CAP * sizeof(int) + fixedB;
    if (hipFuncSetAttribute((const void*)convex_plane_kernel,
                            hipFuncAttributeMaxDynamicSharedMemorySize,
                            (int)smem) != hipSuccess) {
        CAP = 8192;                                  // stay within default 64 KB
        smem = maskB + (size_t)CAP * sizeof(int) + fixedB;
    }
    convex_plane_kernel<<<M, BLOCK, smem, stream>>>(pc, tg, out, N, M, CAP);
}